// Round 6
// baseline (79.250 us; speedup 1.0000x reference)
//
#include <hip/hip_runtime.h>
#include <cstddef>

#define SLEN 8192
#define CIN  32
#define COUT 8
#define BATCH 128
#define BK 4                      // batches per thread
#define LOG2E2 2.885390081777927f // 2*log2(e)

typedef float v2f __attribute__((ext_vector_type(2)));
typedef float v4f __attribute__((ext_vector_type(4)));

__device__ __forceinline__ float exp2_fast(float x) {
    float r; asm("v_exp_f32 %0, %1" : "=v"(r) : "v"(x)); return r;
}
// tanh(x) given v = x * 2*log2(e):  1 - 2/(exp2(v)+1); saturates via rcp(inf)=0.
__device__ __forceinline__ float tanh_scaled(float v) {
    float t = exp2_fast(v);
    return 1.0f - 2.0f * __builtin_amdgcn_rcpf(t + 1.0f);
}

// Kernel 1a: wsum[j,s] = (sum_i w1[i,j,s]) * 2*log2(e)
__global__ __launch_bounds__(256) void lc3_wsum(const float* __restrict__ w1,
                                                float* __restrict__ wsum) {
    __shared__ v4f part[4][64];
    const int tx = threadIdx.x & 63;
    const int ty = threadIdx.x >> 6;
    const int g  = blockIdx.x * 64 + tx;       // float4-output index
    const int j  = g >> 11;
    const int s4 = g & 2047;

    v4f acc = (v4f)(0.f);
    #pragma unroll
    for (int ii = 0; ii < 8; ++ii) {
        const int i = ty * 8 + ii;
        acc += *reinterpret_cast<const v4f*>(
            &w1[(size_t)(i * CIN + j) * SLEN + (size_t)s4 * 4]);
    }
    part[ty][tx] = acc;
    __syncthreads();
    if (ty == 0) {
        v4f r = (part[0][tx] + part[1][tx] + part[2][tx] + part[3][tx]) * LOG2E2;
        *reinterpret_cast<v4f*>(&wsum[(size_t)j * SLEN + (size_t)s4 * 4]) = r;
    }
}

// Kernel 1b: w2t[((sp*32 + j)*8 + o)*2 + si] = w2[(o*32 + j)*8192 + 2*sp + si]
// Per (sp,j) the 16 floats {o0s0,o0s1,o1s0,o1s1,...} are contiguous -> main
// kernel reads them as 4 dwordx4 with immediate offsets, pk-fma-ready.
__global__ __launch_bounds__(256) void lc3_w2t(const float* __restrict__ w2,
                                               float* __restrict__ w2t) {
    const int lane = threadIdx.x & 63;
    const int wv   = threadIdx.x >> 6;          // 0..3
    const int sp   = blockIdx.x * 64 + lane;    // 0..4095
    const int jp   = blockIdx.y * 4 + wv;       // 0..15
    #pragma unroll
    for (int jj = 0; jj < 2; ++jj) {
        const int j = jp * 2 + jj;
        v2f a[COUT];
        #pragma unroll
        for (int o = 0; o < COUT; ++o)
            a[o] = *reinterpret_cast<const v2f*>(&w2[(size_t)(o * CIN + j) * SLEN + sp * 2]);
        float* dst = &w2t[((size_t)sp * CIN + j) * COUT * 2];
        #pragma unroll
        for (int c = 0; c < 4; ++c) {
            v4f q = { a[2*c].x, a[2*c].y, a[2*c+1].x, a[2*c+1].y };
            *reinterpret_cast<v4f*>(&dst[c * 4]) = q;
        }
    }
}

// Kernel 2: thread owns 2 s-positions x BK batches x 8 outs.
// Wave-pairs split the j-reduction (jh=0: j<16, jh=1: j>=16); LDS combine.
__global__ __launch_bounds__(256, 4) void lc3_main(const float* __restrict__ x,
                                                   const float* __restrict__ w2t,
                                                   const float* __restrict__ bias,
                                                   const float* __restrict__ wsum,
                                                   float* __restrict__ out) {
    __shared__ v2f part[BK * COUT][128];
    const int tl = threadIdx.x & 127;
    const int jh = threadIdx.x >> 7;
    const int sp = blockIdx.x * 128 + tl;
    const int s  = sp * 2;
    const int b0 = blockIdx.y * BK;
    const int jb = jh * 16;

    v2f acc[BK][COUT];
    #pragma unroll
    for (int k = 0; k < BK; ++k)
        #pragma unroll
        for (int o = 0; o < COUT; ++o) acc[k][o] = (v2f)(0.f);

    const float* wp  = wsum + (size_t)jb * SLEN + s;
    const float* w2p = w2t + ((size_t)sp * CIN + jb) * COUT * 2;
    const float* xk[BK];
    #pragma unroll
    for (int k = 0; k < BK; ++k)
        xk[k] = x + ((size_t)(b0 + k) * CIN + jb) * SLEN + s;

    #pragma unroll 2
    for (int j = 0; j < 16; ++j) {
        const v2f wsv = *reinterpret_cast<const v2f*>(&wp[(size_t)j * SLEN]);
        const v4f w01 = *reinterpret_cast<const v4f*>(&w2p[j * 16 + 0]);
        const v4f w23 = *reinterpret_cast<const v4f*>(&w2p[j * 16 + 4]);
        const v4f w45 = *reinterpret_cast<const v4f*>(&w2p[j * 16 + 8]);
        const v4f w67 = *reinterpret_cast<const v4f*>(&w2p[j * 16 + 12]);
        #pragma unroll
        for (int k = 0; k < BK; ++k) {
            const v2f xv = *reinterpret_cast<const v2f*>(&xk[k][(size_t)j * SLEN]);
            const v2f v = xv * wsv;            // pk_mul (wsum pre-scaled)
            v2f h;
            h.x = tanh_scaled(v.x);
            h.y = tanh_scaled(v.y);
            acc[k][0] += h * w01.xy;           // v_pk_fma_f32
            acc[k][1] += h * w01.zw;
            acc[k][2] += h * w23.xy;
            acc[k][3] += h * w23.zw;
            acc[k][4] += h * w45.xy;
            acc[k][5] += h * w45.zw;
            acc[k][6] += h * w67.xy;
            acc[k][7] += h * w67.zw;
        }
    }

    if (jh) {
        #pragma unroll
        for (int k = 0; k < BK; ++k)
            #pragma unroll
            for (int o = 0; o < COUT; ++o)
                part[k * COUT + o][tl] = acc[k][o];
    }
    __syncthreads();
    if (!jh) {
        #pragma unroll
        for (int o = 0; o < COUT; ++o) {
            const v2f bv = *reinterpret_cast<const v2f*>(&bias[o * SLEN + s]);
            #pragma unroll
            for (int k = 0; k < BK; ++k) {
                const v2f t = (acc[k][o] + part[k * COUT + o][tl] + bv) * LOG2E2;
                v2f r;
                r.x = tanh_scaled(t.x);
                r.y = tanh_scaled(t.y);
                *reinterpret_cast<v2f*>(&out[((size_t)(b0 + k) * COUT + o) * SLEN + s]) = r;
            }
        }
    }
}

extern "C" void kernel_launch(void* const* d_in, const int* in_sizes, int n_in,
                              void* d_out, int out_size, void* d_ws, size_t ws_size,
                              hipStream_t stream) {
    const float* x    = (const float*)d_in[0];
    const float* w1   = (const float*)d_in[1];
    const float* w2   = (const float*)d_in[2];
    const float* bias = (const float*)d_in[3];
    float* out  = (float*)d_out;
    float* wsum = (float*)d_ws;                              // 1 MB
    float* w2t  = (float*)((char*)d_ws + (size_t)CIN * SLEN * 4); // 8 MB

    // 1a: wsum (scaled). 65536 float4 outputs, 64/block -> 1024 blocks.
    lc3_wsum<<<dim3(CIN * SLEN / 4 / 64), dim3(256), 0, stream>>>(w1, wsum);
    // 1b: w2 transpose. 4096 sp / 64 per wave x 16 j-pairs / 4 waves.
    lc3_w2t<<<dim3(64, 4), dim3(256), 0, stream>>>(w2, w2t);
    // 2: main. (32 s-tiles, 32 b-tiles) = 1024 blocks, 4/CU, 16 waves/CU.
    dim3 grid(SLEN / 256, BATCH / BK);
    lc3_main<<<grid, dim3(256), 0, stream>>>(x, w2t, bias, wsum, out);
}

// Round 7
// 42.785 us; speedup vs baseline: 1.8523x; 1.8523x over previous
//
#include <hip/hip_runtime.h>
#include <cstddef>

#define SLEN 8192
#define CIN  32
#define COUT 8
#define BATCH 128
#define BK 4                      // batches per thread
#define LOG2E2 2.885390081777927f // 2*log2(e)

typedef float v4f __attribute__((ext_vector_type(4)));

__device__ __forceinline__ float exp2_fast(float x) {
    float r; asm("v_exp_f32 %0, %1" : "=v"(r) : "v"(x)); return r;
}
// tanh(u) given v = u * 2*log2(e): 1 - 2/(exp2(v)+1); saturates via rcp(inf)=0.
__device__ __forceinline__ float tanh_scaled(float v) {
    float t = exp2_fast(v);
    return 1.0f - 2.0f * __builtin_amdgcn_rcpf(t + 1.0f);
}

// Kernel 1: wsum[j,s] = (sum_i w1[i,j,s]) * 2*log2(e)
__global__ __launch_bounds__(256) void lc3_wsum(const float* __restrict__ w1,
                                                float* __restrict__ wsum) {
    __shared__ v4f part[4][64];
    const int tx = threadIdx.x & 63;
    const int ty = threadIdx.x >> 6;
    const int g  = blockIdx.x * 64 + tx;       // float4-output index
    const int j  = g >> 11;
    const int s4 = g & 2047;

    v4f acc = (v4f)(0.f);
    #pragma unroll
    for (int ii = 0; ii < 8; ++ii) {
        const int i = ty * 8 + ii;
        acc += *reinterpret_cast<const v4f*>(
            &w1[(size_t)(i * CIN + j) * SLEN + (size_t)s4 * 4]);
    }
    part[ty][tx] = acc;
    __syncthreads();
    if (ty == 0) {
        v4f r = (part[0][tx] + part[1][tx] + part[2][tx] + part[3][tx]) * LOG2E2;
        *reinterpret_cast<v4f*>(&wsum[(size_t)j * SLEN + (size_t)s4 * 4]) = r;
    }
}

// Kernel 2: R1 structure (scalar coalesced, BK=4, no LDS) + 1-deep register
// prefetch across the j-loop: iteration j computes with data loaded at j-1,
// so L2/L3 latency hides under tanh+FMA instead of stalling every iteration.
__global__ __launch_bounds__(256, 4) void lc3_main(const float* __restrict__ x,
                                                   const float* __restrict__ w2,
                                                   const float* __restrict__ bias,
                                                   const float* __restrict__ wsum,
                                                   float* __restrict__ out) {
    const int s  = blockIdx.x * 256 + threadIdx.x;
    const int b0 = blockIdx.y * BK;

    const float* wp = wsum + s;
    const float* xb[BK];
    #pragma unroll
    for (int k = 0; k < BK; ++k) xb[k] = x + ((size_t)(b0 + k) * CIN) * SLEN + s;
    const float* w2b[COUT];
    #pragma unroll
    for (int o = 0; o < COUT; ++o) w2b[o] = w2 + ((size_t)o * CIN) * SLEN + s;

    float acc[BK][COUT];
    #pragma unroll
    for (int k = 0; k < BK; ++k)
        #pragma unroll
        for (int o = 0; o < COUT; ++o) acc[k][o] = 0.f;

    // prefetch j = 0
    float pw = wp[0];
    float px[BK];
    #pragma unroll
    for (int k = 0; k < BK; ++k) px[k] = xb[k][0];
    float pw2[COUT];
    #pragma unroll
    for (int o = 0; o < COUT; ++o) pw2[o] = w2b[o][0];

    #pragma unroll 2
    for (int j = 0; j < CIN; ++j) {
        // issue next iteration's loads first (independent of this iter's math)
        float nw = 0.f, nx[BK], nw2[COUT];
        if (j + 1 < CIN) {
            const size_t off = (size_t)(j + 1) * SLEN;
            nw = wp[off];
            #pragma unroll
            for (int k = 0; k < BK; ++k) nx[k] = xb[k][off];
            #pragma unroll
            for (int o = 0; o < COUT; ++o) nw2[o] = w2b[o][off];
        }

        // compute with prefetched values (wsum pre-scaled by 2*log2e)
        float h[BK];
        #pragma unroll
        for (int k = 0; k < BK; ++k) h[k] = tanh_scaled(px[k] * pw);
        #pragma unroll
        for (int o = 0; o < COUT; ++o)
            #pragma unroll
            for (int k = 0; k < BK; ++k)
                acc[k][o] = fmaf(h[k], pw2[o], acc[k][o]);

        // rotate
        pw = nw;
        #pragma unroll
        for (int k = 0; k < BK; ++k) px[k] = nx[k];
        #pragma unroll
        for (int o = 0; o < COUT; ++o) pw2[o] = nw2[o];
    }

    #pragma unroll
    for (int o = 0; o < COUT; ++o) {
        const float bsc = bias[o * SLEN + s] * LOG2E2;
        #pragma unroll
        for (int k = 0; k < BK; ++k)
            out[((size_t)(b0 + k) * COUT + o) * SLEN + s] =
                tanh_scaled(fmaf(acc[k][o], LOG2E2, bsc));
    }
}

extern "C" void kernel_launch(void* const* d_in, const int* in_sizes, int n_in,
                              void* d_out, int out_size, void* d_ws, size_t ws_size,
                              hipStream_t stream) {
    const float* x    = (const float*)d_in[0];
    const float* w1   = (const float*)d_in[1];
    const float* w2   = (const float*)d_in[2];
    const float* bias = (const float*)d_in[3];
    float* out  = (float*)d_out;
    float* wsum = (float*)d_ws;   // 1 MB scratch

    // wsum: 65536 float4 outputs, 64/block -> 1024 blocks
    lc3_wsum<<<dim3(CIN * SLEN / 4 / 64), dim3(256), 0, stream>>>(w1, wsum);

    // main: (32 s-tiles, 32 b-tiles) = 1024 blocks, 16 waves/CU;
    // linear dispatch puts all 32 b-tiles of one s-tile on the same XCD (bx%8)
    dim3 grid(SLEN / 256, BATCH / BK);
    lc3_main<<<grid, dim3(256), 0, stream>>>(x, w2, bias, wsum, out);
}